// Round 2
// baseline (269.565 us; speedup 1.0000x reference)
//
#include <hip/hip_runtime.h>
#include <hip/hip_bf16.h>

#define EMBED 1024
#define VEC   (EMBED / 4)   // 256 float4 per row

// One block per token. 256 threads, each copies one float4 of the 1024-float
// embedding row. Row read is coalesced (contiguous 4 KB), output write is
// coalesced (contiguous 4 KB). Token id is wave-uniform -> scalar load.
__global__ __launch_bounds__(256) void Embedding_19937238188585_kernel(
    const int* __restrict__ ids,
    const float4* __restrict__ w,
    float4* __restrict__ out)
{
    const int tok = blockIdx.x;
    const int id  = ids[tok];
    const float4* __restrict__ src = w   + (size_t)id  * VEC;
    float4* __restrict__       dst = out + (size_t)tok * VEC;
    dst[threadIdx.x] = src[threadIdx.x];
}

extern "C" void kernel_launch(void* const* d_in, const int* in_sizes, int n_in,
                              void* d_out, int out_size, void* d_ws, size_t ws_size,
                              hipStream_t stream) {
    const int*    ids = (const int*)d_in[0];      // token_ids, int32, [4*4096]
    const float4* w   = (const float4*)d_in[1];   // weights, fp32, [50257, 1024]
    float4*       out = (float4*)d_out;           // fp32, [4, 4096, 1024]

    const int n_tokens = in_sizes[0];             // 16384
    Embedding_19937238188585_kernel<<<n_tokens, 256, 0, stream>>>(ids, w, out);
}